// Round 3
// baseline (278.698 us; speedup 1.0000x reference)
//
#include <hip/hip_runtime.h>

#define BATCH 64
#define M_GT  100
#define M1    101
#define NANCH 8732
#define NPT   4                  // anchors per thread
#define BLOCK 256
#define NTILE (BLOCK * NPT)      // 1024 anchors per block

typedef float vf4 __attribute__((ext_vector_type(4)));  // native vector: OK for nontemporal builtin

__device__ __forceinline__ void store_nt_f4(float* p, vf4 v) {
    __builtin_nontemporal_store(v, reinterpret_cast<vf4*>(p));
}

__global__ __launch_bounds__(BLOCK) void encode_kernel(
    const float* __restrict__ labels,   // [B, M, 5]  fp32
    const float* __restrict__ dboxes,   // [N, 4]     fp32
    float* __restrict__ out_labeled,    // [B, N, 5]  fp32
    float* __restrict__ out_ious)       // [B, M1, N] fp32
{
    __shared__ float s_x1[M1], s_y1[M1], s_x2[M1], s_y2[M1], s_ar[M1], s_cls[M1];
    const int b   = blockIdx.y;
    const int tid = threadIdx.x;

    // Stage GT rows (row 0 = zero pad). Invalid rows (cls==0) get zeroed boxes
    // so IoU evaluates to exactly 0 (inter=0, denom=anchor_area>0) == iou*valid.
    if (tid < M1) {
        float x1 = 0.f, y1 = 0.f, x2 = 0.f, y2 = 0.f, ar = 0.f, cls = 0.f;
        if (tid >= 1) {
            const float* row = labels + ((size_t)b * M_GT + (tid - 1)) * 5;
            cls = row[4];
            if (cls != 0.0f) {
                x1 = row[0]; y1 = row[1]; x2 = row[2]; y2 = row[3];
                ar = (x2 - x1) * (y2 - y1);
            }
        }
        s_x1[tid] = x1; s_y1[tid] = y1; s_x2[tid] = x2; s_y2[tid] = y2;
        s_ar[tid] = ar; s_cls[tid] = cls;
    }
    __syncthreads();

    const int n0 = blockIdx.x * NTILE + tid * NPT;
    if (n0 >= NANCH) return;   // NANCH % 4 == 0 -> whole quad in/out

    // Anchor quad in registers; (n0+i)*4 floats = 16B aligned -> vector loads
    float ax1[NPT], ay1[NPT], ax2[NPT], ay2[NPT], aa[NPT];
    #pragma unroll
    for (int i = 0; i < NPT; ++i) {
        vf4 d = *reinterpret_cast<const vf4*>(dboxes + (size_t)(n0 + i) * 4);
        ax1[i] = d.x; ay1[i] = d.y; ax2[i] = d.z; ay2[i] = d.w;
        aa[i]  = (d.z - d.x) * (d.w - d.y);
    }

    float best[NPT]; int besti[NPT];
    #pragma unroll
    for (int i = 0; i < NPT; ++i) { best[i] = -1.0f; besti[i] = 0; }

    float* irow = out_ious + (size_t)b * M1 * NANCH + n0;

    for (int m = 0; m < M1; ++m) {
        const float gx1 = s_x1[m], gy1 = s_y1[m], gx2 = s_x2[m], gy2 = s_y2[m];
        const float ga  = s_ar[m];
        float iou[NPT];
        #pragma unroll
        for (int i = 0; i < NPT; ++i) {
            float ix1 = fmaxf(gx1, ax1[i]), iy1 = fmaxf(gy1, ay1[i]);
            float ix2 = fminf(gx2, ax2[i]), iy2 = fminf(gy2, ay2[i]);
            float iw = fmaxf(ix2 - ix1, 0.0f), ih = fmaxf(iy2 - iy1, 0.0f);
            float inter = iw * ih;
            iou[i] = inter / (ga + aa[i] - inter);   // exact fp32 div: argmax matches np ref
            if (iou[i] > best[i]) { best[i] = iou[i]; besti[i] = m; }  // strict > = first occurrence
        }
        vf4 w = { iou[0], iou[1], iou[2], iou[3] };
        store_nt_f4(irow + (size_t)m * NANCH, w);    // 16B coalesced streaming store
    }

    // Epilogue: offsets + positive class (zeros for unmatched anchors)
    float lw[NPT * 5];
    #pragma unroll
    for (int i = 0; i < NPT; ++i) {
        const int idx = (best[i] > 0.5f) ? besti[i] : 0;
        float ox = 0.f, oy = 0.f, ow = 0.f, oh = 0.f, pcls = 0.f;
        if (idx != 0) {   // idx>0 implies valid GT row (invalid rows have iou==0)
            const float x1 = s_x1[idx], y1 = s_y1[idx], x2 = s_x2[idx], y2 = s_y2[idx];
            const float aw = ax2[i] - ax1[i], ah = ay2[i] - ay1[i];
            const float acx = 0.5f * (ax1[i] + ax2[i]), acy = 0.5f * (ay1[i] + ay2[i]);
            const float tw = x2 - x1, th = y2 - y1;
            const float tcx = 0.5f * (x1 + x2), tcy = 0.5f * (y1 + y2);
            ox = (tcx - acx) / aw;
            oy = (tcy - acy) / ah;
            ow = __logf(tw / aw);
            oh = __logf(th / ah);
            pcls = s_cls[idx];
        }
        lw[i * 5 + 0] = ox; lw[i * 5 + 1] = oy; lw[i * 5 + 2] = ow;
        lw[i * 5 + 3] = oh; lw[i * 5 + 4] = pcls;
    }
    // 20 contiguous floats = 80B; base byte offset (b*N+n0)*20 is 16B-aligned (n0%4==0)
    float* lrow = out_labeled + ((size_t)b * NANCH + n0) * 5;
    #pragma unroll
    for (int k = 0; k < 5; ++k) {
        vf4 v = { lw[k*4+0], lw[k*4+1], lw[k*4+2], lw[k*4+3] };
        store_nt_f4(lrow + k * 4, v);
    }
}

extern "C" void kernel_launch(void* const* d_in, const int* in_sizes, int n_in,
                              void* d_out, int out_size, void* d_ws, size_t ws_size,
                              hipStream_t stream) {
    const float* labels = (const float*)d_in[0];
    const float* dboxes = (const float*)d_in[1];
    float* out_labeled = (float*)d_out;
    float* out_ious    = out_labeled + (size_t)BATCH * NANCH * 5;

    dim3 grid((NANCH + NTILE - 1) / NTILE, BATCH);
    encode_kernel<<<grid, BLOCK, 0, stream>>>(labels, dboxes, out_labeled, out_ious);
}

// Round 4
// 267.056 us; speedup vs baseline: 1.0436x; 1.0436x over previous
//
#include <hip/hip_runtime.h>

#define BATCH 64
#define M_GT  100
#define M1    101
#define NANCH 8732
#define BLOCK 256

// Role A: iou tile writes. 4 anchors/thread, 1024 anchors * 8 m-rows per block.
#define A_NPT   4
#define A_NTILE 1024
#define A_NX    9     // ceil(8732/1024)
#define A_MCH   8
#define A_NY    13    // ceil(101/8)
#define A_PER_B (A_NX * A_NY)          // 117
#define NBLK_A  (A_PER_B * BATCH)      // 7488

// Role B: argmax + epilogue. 1 anchor/thread.
#define B_NX    35    // ceil(8732/256)
#define NBLK_B  (B_NX * BATCH)         // 2240

#define NBLK (NBLK_A + NBLK_B)         // 9728

__global__ __launch_bounds__(BLOCK, 4) void encode_fat(
    const float* __restrict__ labels,   // [B, M, 5]  fp32
    const float* __restrict__ dboxes,   // [N, 4]     fp32
    float* __restrict__ out_labeled,    // [B, N, 5]  fp32
    float* __restrict__ out_ious)       // [B, M1, N] fp32
{
    __shared__ float s_x1[M1], s_y1[M1], s_x2[M1], s_y2[M1], s_ar[M1], s_cls[M1];
    const int tid = threadIdx.x;
    const int gid = blockIdx.x;

    if (gid < NBLK_B) {
        // ---------------- Role B: argmax over m + epilogue ----------------
        const int b  = gid / B_NX;
        const int nb = gid % B_NX;

        // Stage all 101 GT rows; pad/invalid rows zeroed (IoU -> exactly 0).
        if (tid < M1) {
            float x1 = 0.f, y1 = 0.f, x2 = 0.f, y2 = 0.f, ar = 0.f, cls = 0.f;
            if (tid >= 1) {
                const float* row = labels + ((size_t)b * M_GT + (tid - 1)) * 5;
                cls = row[4];
                if (cls != 0.0f) {
                    x1 = row[0]; y1 = row[1]; x2 = row[2]; y2 = row[3];
                    ar = (x2 - x1) * (y2 - y1);
                }
            }
            s_x1[tid] = x1; s_y1[tid] = y1; s_x2[tid] = x2; s_y2[tid] = y2;
            s_ar[tid] = ar; s_cls[tid] = cls;
        }
        __syncthreads();

        const int n = nb * BLOCK + tid;
        if (n >= NANCH) return;

        const float4 d = *reinterpret_cast<const float4*>(dboxes + (size_t)n * 4);
        const float ax1 = d.x, ay1 = d.y, ax2 = d.z, ay2 = d.w;
        const float aa  = (ax2 - ax1) * (ay2 - ay1);

        float best = -1.0f; int besti = 0;
        for (int m = 0; m < M1; ++m) {
            const float ix1 = fmaxf(s_x1[m], ax1), iy1 = fmaxf(s_y1[m], ay1);
            const float ix2 = fminf(s_x2[m], ax2), iy2 = fminf(s_y2[m], ay2);
            const float iw = fmaxf(ix2 - ix1, 0.0f), ih = fmaxf(iy2 - iy1, 0.0f);
            const float inter = iw * ih;
            // exact fp32 div: bit-matches the reference expression -> argmax ties safe
            const float iou = inter / (s_ar[m] + aa - inter);
            if (iou > best) { best = iou; besti = m; }   // strict > = first-occurrence argmax
        }

        const int idx = (best > 0.5f) ? besti : 0;
        float ox = 0.f, oy = 0.f, ow = 0.f, oh = 0.f, pcls = 0.f;
        if (idx != 0) {   // winner with iou>0.5 is always a valid (cls!=0) row
            const float x1 = s_x1[idx], y1 = s_y1[idx], x2 = s_x2[idx], y2 = s_y2[idx];
            const float aw = ax2 - ax1, ah = ay2 - ay1;
            const float acx = 0.5f * (ax1 + ax2), acy = 0.5f * (ay1 + ay2);
            ox = (0.5f * (x1 + x2) - acx) / aw;
            oy = (0.5f * (y1 + y2) - acy) / ah;
            ow = __logf((x2 - x1) / aw);
            oh = __logf((y2 - y1) / ah);
            pcls = s_cls[idx];
        }
        float* lrow = out_labeled + ((size_t)b * NANCH + n) * 5;
        lrow[0] = ox; lrow[1] = oy; lrow[2] = ow; lrow[3] = oh; lrow[4] = pcls;
    } else {
        // ---------------- Role A: iou tile writes ----------------
        const int g  = gid - NBLK_B;
        const int b  = g / A_PER_B;
        const int r  = g % A_PER_B;
        const int xb = r % A_NX;
        const int yb = r / A_NX;
        const int m0   = yb * A_MCH;
        const int mcnt = min(M1 - m0, A_MCH);

        if (tid < mcnt) {
            const int m = m0 + tid;
            float x1 = 0.f, y1 = 0.f, x2 = 0.f, y2 = 0.f, ar = 0.f;
            if (m >= 1) {
                const float* row = labels + ((size_t)b * M_GT + (m - 1)) * 5;
                if (row[4] != 0.0f) {
                    x1 = row[0]; y1 = row[1]; x2 = row[2]; y2 = row[3];
                    ar = (x2 - x1) * (y2 - y1);
                }
            }
            s_x1[tid] = x1; s_y1[tid] = y1; s_x2[tid] = x2; s_y2[tid] = y2;
            s_ar[tid] = ar;
        }
        __syncthreads();

        const int n0 = xb * A_NTILE + tid * A_NPT;
        if (n0 >= NANCH) return;   // NANCH % 4 == 0 -> whole quad in/out

        float ax1[A_NPT], ay1[A_NPT], ax2[A_NPT], ay2[A_NPT], aa[A_NPT];
        #pragma unroll
        for (int i = 0; i < A_NPT; ++i) {
            const float4 d = *reinterpret_cast<const float4*>(dboxes + (size_t)(n0 + i) * 4);
            ax1[i] = d.x; ay1[i] = d.y; ax2[i] = d.z; ay2[i] = d.w;
            aa[i]  = (d.z - d.x) * (d.w - d.y);
        }

        float* irow = out_ious + ((size_t)b * M1 + m0) * NANCH + n0;
        for (int mm = 0; mm < mcnt; ++mm) {
            const float gx1 = s_x1[mm], gy1 = s_y1[mm], gx2 = s_x2[mm], gy2 = s_y2[mm];
            const float ga  = s_ar[mm];
            float iou[A_NPT];
            #pragma unroll
            for (int i = 0; i < A_NPT; ++i) {
                const float ix1 = fmaxf(gx1, ax1[i]), iy1 = fmaxf(gy1, ay1[i]);
                const float ix2 = fminf(gx2, ax2[i]), iy2 = fminf(gy2, ay2[i]);
                const float iw = fmaxf(ix2 - ix1, 0.0f), ih = fmaxf(iy2 - iy1, 0.0f);
                const float inter = iw * ih;
                // stored value only (tolerance ~1e-2); rcp err ~1e-6. inter==0 -> exact 0.
                iou[i] = inter * __builtin_amdgcn_rcpf(ga + aa[i] - inter);
            }
            float4 w; w.x = iou[0]; w.y = iou[1]; w.z = iou[2]; w.w = iou[3];
            *reinterpret_cast<float4*>(irow + (size_t)mm * NANCH) = w;
        }
    }
}

extern "C" void kernel_launch(void* const* d_in, const int* in_sizes, int n_in,
                              void* d_out, int out_size, void* d_ws, size_t ws_size,
                              hipStream_t stream) {
    const float* labels = (const float*)d_in[0];
    const float* dboxes = (const float*)d_in[1];
    float* out_labeled = (float*)d_out;
    float* out_ious    = out_labeled + (size_t)BATCH * NANCH * 5;

    encode_fat<<<dim3(NBLK), dim3(BLOCK), 0, stream>>>(labels, dboxes, out_labeled, out_ious);
}

// Round 5
// 252.732 us; speedup vs baseline: 1.1027x; 1.0567x over previous
//
#include <hip/hip_runtime.h>

#define BATCH 64
#define M_GT  100
#define M1    101
#define NANCH 8732
#define BLOCK 256
#define NX    35                 // ceil(8732/256) anchor tiles per batch
#define NBLK  (NX * BATCH)       // 2240 blocks = 8.75/CU

// Fused single pass: each thread owns ONE anchor, loops all 101 GT rows,
// computes iou with exact fp32 div ONCE (stored value == argmax value ==
// reference expression bit-for-bit), tracks first-occurrence argmax, then
// does the epilogue. No duplicated IoU compute (round-4 mistake).
__global__ __launch_bounds__(BLOCK, 6) void encode_fused(
    const float* __restrict__ labels,   // [B, M, 5]  fp32
    const float* __restrict__ dboxes,   // [N, 4]     fp32
    float* __restrict__ out_labeled,    // [B, N, 5]  fp32
    float* __restrict__ out_ious)       // [B, M1, N] fp32
{
    __shared__ float s_x1[M1], s_y1[M1], s_x2[M1], s_y2[M1], s_ar[M1], s_cls[M1];
    const int tid = threadIdx.x;
    const int b   = blockIdx.x / NX;
    const int nb  = blockIdx.x % NX;

    // Stage GT rows (row 0 = zero pad). Invalid rows (cls==0) zeroed ->
    // IoU evaluates to exactly 0 (inter=0, denom=anchor_area>0) == iou*valid.
    if (tid < M1) {
        float x1 = 0.f, y1 = 0.f, x2 = 0.f, y2 = 0.f, ar = 0.f, cls = 0.f;
        if (tid >= 1) {
            const float* row = labels + ((size_t)b * M_GT + (tid - 1)) * 5;
            cls = row[4];
            if (cls != 0.0f) {
                x1 = row[0]; y1 = row[1]; x2 = row[2]; y2 = row[3];
                ar = (x2 - x1) * (y2 - y1);
            }
        }
        s_x1[tid] = x1; s_y1[tid] = y1; s_x2[tid] = x2; s_y2[tid] = y2;
        s_ar[tid] = ar; s_cls[tid] = cls;
    }
    __syncthreads();

    const int n = nb * BLOCK + tid;
    if (n >= NANCH) return;

    const float4 d = *reinterpret_cast<const float4*>(dboxes + (size_t)n * 4);
    const float ax1 = d.x, ay1 = d.y, ax2 = d.z, ay2 = d.w;
    const float aa  = (ax2 - ax1) * (ay2 - ay1);

    float* icol = out_ious + (size_t)b * M1 * NANCH + n;

    float best = -1.0f; int besti = 0;
    #pragma unroll 4
    for (int m = 0; m < M1; ++m) {
        const float ix1 = fmaxf(s_x1[m], ax1), iy1 = fmaxf(s_y1[m], ay1);
        const float ix2 = fminf(s_x2[m], ax2), iy2 = fminf(s_y2[m], ay2);
        const float iw = fmaxf(ix2 - ix1, 0.0f), ih = fmaxf(iy2 - iy1, 0.0f);
        const float inter = iw * ih;
        // exact fp32 div: bit-matches the reference -> argmax ties + stored value safe
        const float iou = inter / (s_ar[m] + aa - inter);
        icol[(size_t)m * NANCH] = iou;          // wave writes 256B contiguous per m
        if (iou > best) { best = iou; besti = m; }  // strict > = first-occurrence argmax
    }

    const int idx = (best > 0.5f) ? besti : 0;
    float ox = 0.f, oy = 0.f, ow = 0.f, oh = 0.f, pcls = 0.f;
    if (idx != 0) {   // winner with iou>0.5 is always a valid (cls!=0) row
        const float x1 = s_x1[idx], y1 = s_y1[idx], x2 = s_x2[idx], y2 = s_y2[idx];
        const float aw = ax2 - ax1, ah = ay2 - ay1;
        const float acx = 0.5f * (ax1 + ax2), acy = 0.5f * (ay1 + ay2);
        ox = (0.5f * (x1 + x2) - acx) / aw;
        oy = (0.5f * (y1 + y2) - acy) / ah;
        ow = __logf((x2 - x1) / aw);
        oh = __logf((y2 - y1) / ah);
        pcls = s_cls[idx];
    }
    float* lrow = out_labeled + ((size_t)b * NANCH + n) * 5;
    lrow[0] = ox; lrow[1] = oy; lrow[2] = ow; lrow[3] = oh; lrow[4] = pcls;
}

extern "C" void kernel_launch(void* const* d_in, const int* in_sizes, int n_in,
                              void* d_out, int out_size, void* d_ws, size_t ws_size,
                              hipStream_t stream) {
    const float* labels = (const float*)d_in[0];
    const float* dboxes = (const float*)d_in[1];
    float* out_labeled = (float*)d_out;
    float* out_ious    = out_labeled + (size_t)BATCH * NANCH * 5;

    encode_fused<<<dim3(NBLK), dim3(BLOCK), 0, stream>>>(labels, dboxes, out_labeled, out_ious);
}

// Round 6
// 249.296 us; speedup vs baseline: 1.1179x; 1.0138x over previous
//
#include <hip/hip_runtime.h>

#define BATCH 64
#define M_GT  100
#define M1    101
#define NANCH 8732
#define BLOCK 256
#define NPT   2                    // anchors per thread
#define NX    18                   // ceil(8732 / (256*2))
#define NBLK  (NX * BATCH)         // 1152 blocks = 4.5/CU
#define TROW  8                    // floats per preprocessed GT row (32B aligned)

typedef float vf2 __attribute__((ext_vector_type(2)));

// Prep: build padded GT table in d_ws. Row layout: {x1,y1,x2,y2,area_or_inf,cls,0,0}.
// Pad row (m=0) and invalid rows (cls==0) get area=+inf -> iou = inter/inf = +0
// exactly, reproducing the reference's iou*valid masking with no per-iter branch.
__global__ __launch_bounds__(128) void prep_table(
    const float* __restrict__ labels,   // [B, M, 5]
    float* __restrict__ tab)            // [B, M1, TROW]
{
    const int b = blockIdx.x;
    const int m = threadIdx.x;
    if (m >= M1) return;
    float x1 = 0.f, y1 = 0.f, x2 = 0.f, y2 = 0.f, cls = 0.f;
    float ar = __builtin_inff();
    if (m >= 1) {
        const float* row = labels + ((size_t)b * M_GT + (m - 1)) * 5;
        x1 = row[0]; y1 = row[1]; x2 = row[2]; y2 = row[3]; cls = row[4];
        if (cls != 0.0f) ar = (x2 - x1) * (y2 - y1);
    }
    float* t = tab + ((size_t)b * M1 + m) * TROW;
    t[0] = x1; t[1] = y1; t[2] = x2; t[3] = y2;
    t[4] = ar; t[5] = cls; t[6] = 0.f; t[7] = 0.f;
}

__global__ __launch_bounds__(BLOCK, 4) void encode_main(
    const float* __restrict__ tab,      // [B, M1, TROW] (uniform reads -> s_load)
    const float* __restrict__ dboxes,   // [N, 4]
    float* __restrict__ out_labeled,    // [B, N, 5]
    float* __restrict__ out_ious)       // [B, M1, N]
{
    const int tid = threadIdx.x;
    const int b   = blockIdx.x / NX;
    const int nb  = blockIdx.x % NX;
    const int n0  = nb * (BLOCK * NPT) + tid * NPT;
    if (n0 >= NANCH) return;           // NANCH even -> whole pair in/out

    // Anchor pair in registers (float4 loads, 16B aligned)
    float ax1[NPT], ay1[NPT], ax2[NPT], ay2[NPT], aa[NPT];
    #pragma unroll
    for (int i = 0; i < NPT; ++i) {
        const float4 d = *reinterpret_cast<const float4*>(dboxes + (size_t)(n0 + i) * 4);
        ax1[i] = d.x; ay1[i] = d.y; ax2[i] = d.z; ay2[i] = d.w;
        aa[i]  = (d.z - d.x) * (d.w - d.y);
    }

    const float* trow = tab + (size_t)b * M1 * TROW;
    float* irow = out_ious + (size_t)b * M1 * NANCH + n0;

    // best=-1: m=0 (pad row) yields iou=+0 > -1 -> besti=0 baseline; thereafter
    // strict > = numpy first-occurrence argmax.
    float best[NPT]; int besti[NPT];
    #pragma unroll
    for (int i = 0; i < NPT; ++i) { best[i] = -1.0f; besti[i] = 0; }

    #pragma unroll 4
    for (int m = 0; m < M1; ++m) {
        // wave-uniform table reads: scalarize to s_load, fold as SGPR operands
        const float gx1 = trow[0], gy1 = trow[1], gx2 = trow[2], gy2 = trow[3];
        const float ga  = trow[4];
        trow += TROW;
        float iou[NPT];
        #pragma unroll
        for (int i = 0; i < NPT; ++i) {
            const float ix1 = fmaxf(gx1, ax1[i]), iy1 = fmaxf(gy1, ay1[i]);
            const float ix2 = fminf(gx2, ax2[i]), iy2 = fminf(gy2, ay2[i]);
            const float iw = fmaxf(ix2 - ix1, 0.0f), ih = fmaxf(iy2 - iy1, 0.0f);
            const float inter = iw * ih;
            // exact fp32 div: bit-matches reference -> stored value AND argmax ties safe
            iou[i] = inter / (ga + aa[i] - inter);
            if (iou[i] > best[i]) { best[i] = iou[i]; besti[i] = m; }
        }
        vf2 w = { iou[0], iou[1] };
        *reinterpret_cast<vf2*>(irow) = w;     // 8B/lane -> 512B per wave-instr
        irow += NANCH;
    }

    // Epilogue
    float lw[NPT * 5];
    #pragma unroll
    for (int i = 0; i < NPT; ++i) {
        const int idx = (best[i] > 0.5f) ? besti[i] : 0;
        float ox = 0.f, oy = 0.f, ow = 0.f, oh = 0.f, pcls = 0.f;
        if (idx != 0) {   // iou>0.5 winner is always a valid (cls!=0) row
            const float* r = tab + ((size_t)b * M1 + idx) * TROW;
            const float x1 = r[0], y1 = r[1], x2 = r[2], y2 = r[3];
            const float aw = ax2[i] - ax1[i], ah = ay2[i] - ay1[i];
            const float acx = 0.5f * (ax1[i] + ax2[i]), acy = 0.5f * (ay1[i] + ay2[i]);
            ox = (0.5f * (x1 + x2) - acx) / aw;
            oy = (0.5f * (y1 + y2) - acy) / ah;
            ow = __logf((x2 - x1) / aw);
            oh = __logf((y2 - y1) / ah);
            pcls = r[5];
        }
        lw[i * 5 + 0] = ox; lw[i * 5 + 1] = oy; lw[i * 5 + 2] = ow;
        lw[i * 5 + 3] = oh; lw[i * 5 + 4] = pcls;
    }
    // 10 contiguous floats; byte base ((b*N+n0)*5*4) is 8B aligned (n0 even)
    float* lrow = out_labeled + ((size_t)b * NANCH + n0) * 5;
    #pragma unroll
    for (int k = 0; k < 5; ++k) {
        vf2 v = { lw[k * 2], lw[k * 2 + 1] };
        *reinterpret_cast<vf2*>(lrow + k * 2) = v;
    }
}

extern "C" void kernel_launch(void* const* d_in, const int* in_sizes, int n_in,
                              void* d_out, int out_size, void* d_ws, size_t ws_size,
                              hipStream_t stream) {
    const float* labels = (const float*)d_in[0];
    const float* dboxes = (const float*)d_in[1];
    float* out_labeled = (float*)d_out;
    float* out_ious    = out_labeled + (size_t)BATCH * NANCH * 5;
    float* tab         = (float*)d_ws;   // 64*101*8*4 = 207 KB << ws_size (~948 MB)

    prep_table<<<dim3(BATCH), dim3(128), 0, stream>>>(labels, tab);
    encode_main<<<dim3(NBLK), dim3(BLOCK), 0, stream>>>(tab, dboxes, out_labeled, out_ious);
}

// Round 7
// 248.407 us; speedup vs baseline: 1.1219x; 1.0036x over previous
//
#include <hip/hip_runtime.h>

#define BATCH 64
#define M_GT  100
#define M1    101
#define NANCH 8732
#define BLOCK 256
#define NPT   4                    // anchors per thread -> dwordx4 stores
#define NTILE (BLOCK * NPT)        // 1024
#define NX    9                    // ceil(8732/1024)
#define NBLK  (NX * BATCH)         // 576 blocks
#define TROW  8                    // floats per preprocessed GT row

// Prep: padded GT table in d_ws. Row: {x1,y1,x2,y2,area_or_inf,cls,0,0}.
// Pad row (m=0) and invalid rows (cls==0) get area=+inf ->
// iou = inter * rcp(inf) = inter * 0 = +0 exactly (masking), never NaN.
__global__ __launch_bounds__(128) void prep_table(
    const float* __restrict__ labels,   // [B, M, 5]
    float* __restrict__ tab)            // [B, M1, TROW]
{
    const int b = blockIdx.x;
    const int m = threadIdx.x;
    if (m >= M1) return;
    float x1 = 0.f, y1 = 0.f, x2 = 0.f, y2 = 0.f, cls = 0.f;
    float ar = __builtin_inff();
    if (m >= 1) {
        const float* row = labels + ((size_t)b * M_GT + (m - 1)) * 5;
        x1 = row[0]; y1 = row[1]; x2 = row[2]; y2 = row[3]; cls = row[4];
        if (cls != 0.0f) ar = (x2 - x1) * (y2 - y1);
    }
    float* t = tab + ((size_t)b * M1 + m) * TROW;
    t[0] = x1; t[1] = y1; t[2] = x2; t[3] = y2;
    t[4] = ar; t[5] = cls; t[6] = 0.f; t[7] = 0.f;
}

__global__ __launch_bounds__(BLOCK) void encode_main(
    const float* __restrict__ tab,      // [B, M1, TROW] (block-uniform -> s_load)
    const float* __restrict__ dboxes,   // [N, 4]
    float* __restrict__ out_labeled,    // [B, N, 5]
    float* __restrict__ out_ious)       // [B, M1, N]
{
    const int tid = threadIdx.x;
    const int b   = blockIdx.x / NX;
    const int nb  = blockIdx.x % NX;
    const int n0  = nb * NTILE + tid * NPT;
    if (n0 >= NANCH) return;           // NANCH % 4 == 0 -> whole quad in/out

    float ax1[NPT], ay1[NPT], ax2[NPT], ay2[NPT], aa[NPT];
    #pragma unroll
    for (int i = 0; i < NPT; ++i) {
        const float4 d = *reinterpret_cast<const float4*>(dboxes + (size_t)(n0 + i) * 4);
        ax1[i] = d.x; ay1[i] = d.y; ax2[i] = d.z; ay2[i] = d.w;
        aa[i]  = (d.z - d.x) * (d.w - d.y);
    }

    const float* trow = tab + (size_t)b * M1 * TROW;
    float* irow = out_ious + (size_t)b * M1 * NANCH + n0;

    // best=-1: pad rows give iou=+0, first m wins only via strict > (numpy argmax).
    float best[NPT]; int besti[NPT];
    #pragma unroll
    for (int i = 0; i < NPT; ++i) { best[i] = -1.0f; besti[i] = 0; }

    #pragma unroll 2
    for (int m = 0; m < M1; ++m) {
        const float gx1 = trow[0], gy1 = trow[1], gx2 = trow[2], gy2 = trow[3];
        const float ga  = trow[4];
        trow += TROW;
        float iou[NPT];
        #pragma unroll
        for (int i = 0; i < NPT; ++i) {
            const float ix1 = fmaxf(gx1, ax1[i]), iy1 = fmaxf(gy1, ay1[i]);
            const float ix2 = fminf(gx2, ax2[i]), iy2 = fminf(gy2, ay2[i]);
            const float iw = fmaxf(ix2 - ix1, 0.0f), ih = fmaxf(iy2 - iy1, 0.0f);
            const float inter = iw * ih;
            // rcp for stored value AND argmax: validated by round-3 pass (same absmax)
            iou[i] = inter * __builtin_amdgcn_rcpf(ga + aa[i] - inter);
            if (iou[i] > best[i]) { best[i] = iou[i]; besti[i] = m; }
        }
        float4 w; w.x = iou[0]; w.y = iou[1]; w.z = iou[2]; w.w = iou[3];
        *reinterpret_cast<float4*>(irow) = w;   // 1KB per wave-instr
        irow += NANCH;
    }

    // Epilogue
    float lw[NPT * 5];
    #pragma unroll
    for (int i = 0; i < NPT; ++i) {
        const int idx = (best[i] > 0.5f) ? besti[i] : 0;
        float ox = 0.f, oy = 0.f, ow = 0.f, oh = 0.f, pcls = 0.f;
        if (idx != 0) {   // iou>0.5 winner is always a valid (cls!=0) row
            const float* r = tab + ((size_t)b * M1 + idx) * TROW;
            const float x1 = r[0], y1 = r[1], x2 = r[2], y2 = r[3];
            const float aw = ax2[i] - ax1[i], ah = ay2[i] - ay1[i];
            const float acx = 0.5f * (ax1[i] + ax2[i]), acy = 0.5f * (ay1[i] + ay2[i]);
            ox = (0.5f * (x1 + x2) - acx) / aw;
            oy = (0.5f * (y1 + y2) - acy) / ah;
            ow = __logf((x2 - x1) / aw);
            oh = __logf((y2 - y1) / ah);
            pcls = r[5];
        }
        lw[i * 5 + 0] = ox; lw[i * 5 + 1] = oy; lw[i * 5 + 2] = ow;
        lw[i * 5 + 3] = oh; lw[i * 5 + 4] = pcls;
    }
    // 20 contiguous floats = 80B, 16B-aligned (n0 % 4 == 0)
    float* lrow = out_labeled + ((size_t)b * NANCH + n0) * 5;
    #pragma unroll
    for (int k = 0; k < 5; ++k) {
        float4 v; v.x = lw[k*4]; v.y = lw[k*4+1]; v.z = lw[k*4+2]; v.w = lw[k*4+3];
        *reinterpret_cast<float4*>(lrow + k * 4) = v;
    }
}

extern "C" void kernel_launch(void* const* d_in, const int* in_sizes, int n_in,
                              void* d_out, int out_size, void* d_ws, size_t ws_size,
                              hipStream_t stream) {
    const float* labels = (const float*)d_in[0];
    const float* dboxes = (const float*)d_in[1];
    float* out_labeled = (float*)d_out;
    float* out_ious    = out_labeled + (size_t)BATCH * NANCH * 5;
    float* tab         = (float*)d_ws;   // 207 KB << ws_size

    prep_table<<<dim3(BATCH), dim3(128), 0, stream>>>(labels, tab);
    encode_main<<<dim3(NBLK), dim3(BLOCK), 0, stream>>>(tab, dboxes, out_labeled, out_ious);
}